// Round 1
// baseline (1853.565 us; speedup 1.0000x reference)
//
#include <hip/hip_runtime.h>
#include <stdint.h>

// Problem constants
// B=256, S=512, ENC=256, DEC=256, ATTN=128, H=48
#define LOG2E 1.4426950408889634f

__device__ __forceinline__ uint32_t bf16r(float x){
  uint32_t u = __float_as_uint(x);
  return (u + 0x7fffu + ((u >> 16) & 1u)) >> 16;   // RNE round to bf16
}
__device__ __forceinline__ uint32_t pack2(float lo, float hi){
  return bf16r(lo) | (bf16r(hi) << 16);
}
__device__ __forceinline__ float unlo(uint32_t u){ return __uint_as_float(u << 16); }
__device__ __forceinline__ float unhi(uint32_t u){ return __uint_as_float(u & 0xffff0000u); }
__device__ __forceinline__ float bf2f(unsigned short w){ return __uint_as_float(((uint32_t)w) << 16); }

__device__ __forceinline__ float fexp2(float x){ return __builtin_amdgcn_exp2f(x); }
__device__ __forceinline__ float frcp(float x){ return __builtin_amdgcn_rcpf(x); }
__device__ __forceinline__ float ftanh(float x){
  float e = fexp2(x * (2.0f * LOG2E));   // exp(2x)
  return 1.0f - 2.0f * frcp(e + 1.0f);
}
__device__ __forceinline__ float fsig(float x){
  return frcp(1.0f + fexp2(-x * LOG2E));
}
__device__ __forceinline__ float wave_max(float x){
  #pragma unroll
  for(int o = 32; o; o >>= 1) x = fmaxf(x, __shfl_xor(x, o, 64));
  return x;
}
__device__ __forceinline__ float wave_sum(float x){
  #pragma unroll
  for(int o = 32; o; o >>= 1) x += __shfl_xor(x, o, 64);
  return x;
}

// -------- K1: enc fp32 -> bf16 pairs (layout [b][s][e/2] as uint32) --------
__global__ __launch_bounds__(256) void k_enc_bf16(const float* __restrict__ enc,
                                                  uint4* __restrict__ encb4){
  int idx = blockIdx.x * 256 + threadIdx.x;   // 4,194,304 threads, 8 floats each
  const float4* e4 = (const float4*)enc;
  float4 f0 = e4[(size_t)idx * 2];
  float4 f1 = e4[(size_t)idx * 2 + 1];
  encb4[idx] = make_uint4(pack2(f0.x, f0.y), pack2(f0.z, f0.w),
                          pack2(f1.x, f1.y), pack2(f1.z, f1.w));
}

// -------- K2: pack gate weights. Thread-j of main kernel computes rows j and j+512.
// Wq_ih[k4][j] (uint4) packs W_ih cols k=1+4k4+{0..3} for rows (j, j+512).
// Wq_hh[k4][j] packs W_hh cols k=4k4+{0..3}. Wp0[j] packs W_ih col 0. --------
__global__ __launch_bounds__(256) void k_pack_w(const float* __restrict__ W_ih,
                                                const float* __restrict__ W_hh,
                                                uint32_t* __restrict__ Wp0,
                                                uint4* __restrict__ Wq_ih,
                                                uint4* __restrict__ Wq_hh){
  int gid = blockIdx.x * 256 + threadIdx.x;   // 65536 threads
  if(gid < 512){
    Wp0[gid] = pack2(W_ih[gid * 257], W_ih[(gid + 512) * 257]);
  }
  if(gid < 32768){
    int k4 = gid >> 9, j = gid & 511;
    uint32_t r[4];
    #pragma unroll
    for(int m = 0; m < 4; ++m){
      int k = 1 + 4 * k4 + m;
      r[m] = pack2(W_ih[j * 257 + k], W_ih[(j + 512) * 257 + k]);
    }
    Wq_ih[k4 * 512 + j] = make_uint4(r[0], r[1], r[2], r[3]);
  } else {
    int g2 = gid - 32768;
    int k4 = g2 >> 9, j = g2 & 511;
    uint32_t r[4];
    #pragma unroll
    for(int m = 0; m < 4; ++m){
      int k = 4 * k4 + m;
      r[m] = pack2(W_hh[j * 256 + k], W_hh[(j + 512) * 256 + k]);
    }
    Wq_hh[k4 * 512 + j] = make_uint4(r[0], r[1], r[2], r[3]);
  }
}

// -------- K3: enc_proj = enc @ W_enc, fp32 accumulate, output bf16 pairs
// ep layout: [b][a2][s] uint32 where a2 = a/2 (pairs 2a2, 2a2+1), s-contiguous --------
__global__ __launch_bounds__(256) void k_enc_proj(const float* __restrict__ enc,
                                                  const float* __restrict__ W_enc,
                                                  uint32_t* __restrict__ ep){
  __shared__ float Wl[128][132];   // k-chunk x a (+pad)
  __shared__ float Al[64][132];    // s rows x k-chunk (+pad)
  int tid = threadIdx.x;
  int b = blockIdx.x >> 3;
  int st = (blockIdx.x & 7) * 64;
  int tr = tid & 15, tc = tid >> 4;   // tr: a-groups, tc: s-group (4 rows)
  float acc[4][8];
  #pragma unroll
  for(int r = 0; r < 4; ++r)
    #pragma unroll
    for(int i = 0; i < 8; ++i) acc[r][i] = 0.0f;

  for(int kc = 0; kc < 2; ++kc){
    __syncthreads();
    #pragma unroll 8
    for(int i = 0; i < 64; ++i){
      int flat = i * 256 + tid; int kr = flat >> 7, a = flat & 127;
      Wl[kr][a] = W_enc[(kc * 128 + kr) * 128 + a];
    }
    #pragma unroll 8
    for(int i = 0; i < 32; ++i){
      int flat = i * 256 + tid; int row = flat >> 7, col = flat & 127;
      Al[row][col] = enc[((size_t)(b * 512 + st + row)) * 256 + kc * 128 + col];
    }
    __syncthreads();
    for(int k0 = 0; k0 < 128; k0 += 4){
      float4 a0 = *(const float4*)&Al[4 * tc + 0][k0];
      float4 a1 = *(const float4*)&Al[4 * tc + 1][k0];
      float4 a2 = *(const float4*)&Al[4 * tc + 2][k0];
      float4 a3 = *(const float4*)&Al[4 * tc + 3][k0];
      #pragma unroll
      for(int kk = 0; kk < 4; ++kk){
        float4 w0 = *(const float4*)&Wl[k0 + kk][4 * tr];
        float4 w1 = *(const float4*)&Wl[k0 + kk][64 + 4 * tr];
        float av[4];
        av[0] = (&a0.x)[kk]; av[1] = (&a1.x)[kk]; av[2] = (&a2.x)[kk]; av[3] = (&a3.x)[kk];
        #pragma unroll
        for(int r = 0; r < 4; ++r){
          acc[r][0] += av[r] * w0.x; acc[r][1] += av[r] * w0.y;
          acc[r][2] += av[r] * w0.z; acc[r][3] += av[r] * w0.w;
          acc[r][4] += av[r] * w1.x; acc[r][5] += av[r] * w1.y;
          acc[r][6] += av[r] * w1.z; acc[r][7] += av[r] * w1.w;
        }
      }
    }
  }
  #pragma unroll
  for(int r = 0; r < 4; ++r){
    int s = st + 4 * tc + r;
    #pragma unroll
    for(int p = 0; p < 4; ++p){
      int a2i = (p < 2) ? (2 * tr + p) : (32 + 2 * tr + (p - 2));
      ep[((size_t)b * 64 + a2i) * 512 + s] = pack2(acc[r][2 * p], acc[r][2 * p + 1]);
    }
  }
}

// -------- Main: one workgroup per batch element runs all 48 timesteps --------
template<bool ENCB>
__global__ __launch_bounds__(512) void k_main(
    const float* __restrict__ enc,        // fp32 [B][S][ENC]
    const uint32_t* __restrict__ encb,    // bf16 pairs [B][S][128] (if ENCB)
    const uint32_t* __restrict__ ep,      // bf16 pairs [B][64][512]
    const float* __restrict__ h0, const float* __restrict__ c0,
    const float* __restrict__ W_dec, const float* __restrict__ v,
    const uint32_t* __restrict__ Wp0, const uint4* __restrict__ Wq_ih,
    const uint4* __restrict__ Wq_hh,
    const float* __restrict__ b_ih, const float* __restrict__ b_hh,
    const float* __restrict__ W_out, const float* __restrict__ b_out,
    float* __restrict__ out)
{
  __shared__ unsigned short Wd[128][260];            // W_dec^T bf16 [a][k], +pad
  __shared__ __align__(16) float h_l[256];
  __shared__ __align__(16) float c_l[256];
  __shared__ __align__(16) float ctx[256];
  __shared__ float bcomb[1024];
  __shared__ __align__(16) float4 dvpack[64];        // (dp[2a2], v[2a2], dp[2a2+1], v[2a2+1])
  __shared__ float dpp[4][128];
  __shared__ __align__(16) float4 scp4[4][128];      // score partials [q][sb] rows 4sb..4sb+3
  __shared__ float attn_l[512];
  __shared__ __align__(16) float4 ctxp4[8][64];      // context partials [g][e/4]
  __shared__ float sigf[256], sigo[256];
  __shared__ float red1[8], red2[8];
  __shared__ float vl[128], Wo[256];
  __shared__ float misc[2];                          // [0]=prev pred, [1]=b_out

  const int tid = threadIdx.x;
  const int b = blockIdx.x;
  const int lane = tid & 63, wid = tid >> 6;

  // ---- init ----
  #pragma unroll 8
  for(int i = 0; i < 64; ++i){
    int flat = i * 512 + tid;              // 32768 = 256k x 128a
    int k = flat >> 7, a = flat & 127;
    Wd[a][k] = (unsigned short)bf16r(W_dec[flat]);
  }
  if(tid < 128) vl[tid] = v[tid];
  if(tid < 256){
    Wo[tid] = W_out[tid];
    h_l[tid] = h0[b * 256 + tid];
    c_l[tid] = c0[b * 256 + tid];
  }
  bcomb[tid] = b_ih[tid] + b_hh[tid];
  bcomb[tid + 512] = b_ih[tid + 512] + b_hh[tid + 512];
  if(tid == 0){ misc[0] = 0.0f; misc[1] = b_out[0]; }
  __syncthreads();

  const uint32_t* ep_b = ep + (size_t)b * 64 * 512;
  const uint32_t* encb_b = ENCB ? (encb + (size_t)b * 512 * 128) : (const uint32_t*)nullptr;
  const float* enc_b = enc + (size_t)b * 512 * 256;
  float* attn_out_b = out + 12288 + (size_t)b * 48 * 512;

  for(int t = 0; t < 48; ++t){
    // ---- dec_proj = h @ W_dec ----
    {
      int a = tid & 127, g = tid >> 7;
      const float4* h4 = (const float4*)h_l;
      float acc = 0.0f;
      #pragma unroll
      for(int kk = 0; kk < 16; ++kk){
        ushort4 w4 = *(const ushort4*)&Wd[a][g * 64 + kk * 4];
        float4 hh = h4[g * 16 + kk];
        acc += bf2f(w4.x) * hh.x + bf2f(w4.y) * hh.y + bf2f(w4.z) * hh.z + bf2f(w4.w) * hh.w;
      }
      dpp[g][a] = acc;
    }
    __syncthreads();
    if(tid < 64){
      float d0 = dpp[0][2*tid]   + dpp[1][2*tid]   + dpp[2][2*tid]   + dpp[3][2*tid];
      float d1 = dpp[0][2*tid+1] + dpp[1][2*tid+1] + dpp[2][2*tid+1] + dpp[3][2*tid+1];
      dvpack[tid] = make_float4(d0, vl[2*tid], d1, vl[2*tid+1]);
    }
    __syncthreads();

    // ---- scores: v . tanh(enc_proj + dec_proj) ; thread (sb,q): rows 4sb..4sb+3, a2 in [16q,16q+16) ----
    {
      int sb = tid & 127, q = tid >> 7;
      float sc0 = 0, sc1 = 0, sc2 = 0, sc3 = 0;
      const uint4* ep4 = (const uint4*)ep_b;   // [a2][128] of uint4 (4 s per uint4)
      #pragma unroll 4
      for(int i = 0; i < 16; ++i){
        int a2 = q * 16 + i;
        uint4 u = ep4[a2 * 128 + sb];
        float4 dv = dvpack[a2];
        sc0 += dv.y * ftanh(unlo(u.x) + dv.x) + dv.w * ftanh(unhi(u.x) + dv.z);
        sc1 += dv.y * ftanh(unlo(u.y) + dv.x) + dv.w * ftanh(unhi(u.y) + dv.z);
        sc2 += dv.y * ftanh(unlo(u.z) + dv.x) + dv.w * ftanh(unhi(u.z) + dv.z);
        sc3 += dv.y * ftanh(unlo(u.w) + dv.x) + dv.w * ftanh(unhi(u.w) + dv.z);
      }
      scp4[q][sb] = make_float4(sc0, sc1, sc2, sc3);
    }
    __syncthreads();

    // ---- softmax over S (thread tid owns s=tid) ----
    float sc;
    {
      const float* scf = (const float*)scp4;   // [q][s] flat: q*512 + s
      sc = scf[tid] + scf[512 + tid] + scf[1024 + tid] + scf[1536 + tid];
    }
    {
      float m = wave_max(sc);
      if(lane == 0) red1[wid] = m;
    }
    __syncthreads();
    float M = red1[0];
    #pragma unroll
    for(int i = 1; i < 8; ++i) M = fmaxf(M, red1[i]);
    float w = fexp2((sc - M) * LOG2E);
    {
      float sw = wave_sum(w);
      if(lane == 0) red2[wid] = sw;
    }
    __syncthreads();
    float L = red2[0];
    #pragma unroll
    for(int i = 1; i < 8; ++i) L += red2[i];
    float aw = w * frcp(L);
    attn_l[tid] = aw;
    attn_out_b[t * 512 + tid] = aw;
    __syncthreads();

    // ---- context = attn @ enc ; thread (e4i,g): e=4*e4i..+3, s in [64g, 64g+64) ----
    {
      int e4i = tid & 63, g = tid >> 6;
      float a0 = 0, a1 = 0, a2a = 0, a3 = 0;
      if(ENCB){
        const uint2* eb = (const uint2*)encb_b;
        #pragma unroll 4
        for(int i = 0; i < 64; ++i){
          int s = g * 64 + i;
          float at = attn_l[s];
          uint2 u = eb[s * 64 + e4i];
          a0 += at * unlo(u.x); a1 += at * unhi(u.x);
          a2a += at * unlo(u.y); a3 += at * unhi(u.y);
        }
      } else {
        const float4* ef = (const float4*)enc_b;
        #pragma unroll 4
        for(int i = 0; i < 64; ++i){
          int s = g * 64 + i;
          float at = attn_l[s];
          float4 f = ef[s * 64 + e4i];
          a0 += at * f.x; a1 += at * f.y; a2a += at * f.z; a3 += at * f.w;
        }
      }
      ctxp4[g][e4i] = make_float4(a0, a1, a2a, a3);
    }
    __syncthreads();
    if(tid < 256){
      const float* cf = (const float*)ctxp4;   // [g][e] flat: g*256 + e
      float s = 0;
      #pragma unroll
      for(int g = 0; g < 8; ++g) s += cf[g * 256 + tid];
      ctx[tid] = s;
    }
    __syncthreads();

    // ---- gates: thread j computes rows j and j+512 ----
    {
      float acc0 = bcomb[tid], acc1 = bcomb[tid + 512];
      float x0 = misc[0];
      uint32_t w0 = Wp0[tid];
      acc0 += x0 * unlo(w0); acc1 += x0 * unhi(w0);
      const float4* c4 = (const float4*)ctx;
      const float4* h4 = (const float4*)h_l;
      #pragma unroll 4
      for(int k4 = 0; k4 < 64; ++k4){
        uint4 q = Wq_ih[k4 * 512 + tid];
        float4 x = c4[k4];
        acc0 += x.x * unlo(q.x) + x.y * unlo(q.y) + x.z * unlo(q.z) + x.w * unlo(q.w);
        acc1 += x.x * unhi(q.x) + x.y * unhi(q.y) + x.z * unhi(q.z) + x.w * unhi(q.w);
      }
      #pragma unroll 4
      for(int k4 = 0; k4 < 64; ++k4){
        uint4 q = Wq_hh[k4 * 512 + tid];
        float4 x = h4[k4];
        acc0 += x.x * unlo(q.x) + x.y * unlo(q.y) + x.z * unlo(q.z) + x.w * unlo(q.w);
        acc1 += x.x * unhi(q.x) + x.y * unhi(q.y) + x.z * unhi(q.z) + x.w * unhi(q.w);
      }
      // tid<256: acc0=i, acc1=g ; tid>=256: acc0=f, acc1=o
      if(tid >= 256){
        sigf[tid - 256] = fsig(acc0);
        sigo[tid - 256] = fsig(acc1);
      }
      float si = fsig(acc0), tg = ftanh(acc1);
      __syncthreads();
      if(tid < 256){
        float cn = sigf[tid] * c_l[tid] + si * tg;
        float hn = sigo[tid] * ftanh(cn);
        c_l[tid] = cn; h_l[tid] = hn;
        float p = hn * Wo[tid];
        p = wave_sum(p);
        if(lane == 0) red1[wid] = p;
      }
    }
    __syncthreads();
    if(tid == 0){
      float pr = red1[0] + red1[1] + red1[2] + red1[3] + misc[1];
      out[b * 48 + t] = pr;
      misc[0] = pr;
    }
    __syncthreads();
  }
}

extern "C" void kernel_launch(void* const* d_in, const int* in_sizes, int n_in,
                              void* d_out, int out_size, void* d_ws, size_t ws_size,
                              hipStream_t stream) {
  (void)in_sizes; (void)n_in; (void)out_size;
  const float* enc  = (const float*)d_in[0];
  const float* h0   = (const float*)d_in[1];
  const float* c0   = (const float*)d_in[2];
  const float* Wenc = (const float*)d_in[3];
  const float* Wdec = (const float*)d_in[4];
  const float* v    = (const float*)d_in[5];
  const float* Wih  = (const float*)d_in[6];
  const float* Whh  = (const float*)d_in[7];
  const float* bih  = (const float*)d_in[8];
  const float* bhh  = (const float*)d_in[9];
  const float* Wout = (const float*)d_in[10];
  const float* bout = (const float*)d_in[11];
  float* out = (float*)d_out;
  uint8_t* ws = (uint8_t*)d_ws;

  const size_t SZ_ENCB = 67108864ull;   // 33,554,432 bf16
  const size_t SZ_EP   = 33554432ull;   // 8,388,608 uint32
  const size_t SZ_WP0  = 2048ull;
  const size_t SZ_WQ   = 524288ull;     // 64*512*16
  const bool big = ws_size >= SZ_ENCB + SZ_EP + SZ_WP0 + 2 * SZ_WQ;

  uint8_t* p = ws;
  uint32_t* encb = nullptr;
  if(big){ encb = (uint32_t*)p; p += SZ_ENCB; }
  uint32_t* ep   = (uint32_t*)p; p += SZ_EP;
  uint32_t* Wp0  = (uint32_t*)p; p += SZ_WP0;
  uint4*    Wqih = (uint4*)p;    p += SZ_WQ;
  uint4*    Wqhh = (uint4*)p;    p += SZ_WQ;

  if(big) k_enc_bf16<<<dim3(16384), dim3(256), 0, stream>>>(enc, (uint4*)encb);
  k_pack_w<<<dim3(256), dim3(256), 0, stream>>>(Wih, Whh, Wp0, Wqih, Wqhh);
  k_enc_proj<<<dim3(2048), dim3(256), 0, stream>>>(enc, Wenc, ep);
  if(big)
    k_main<true><<<dim3(256), dim3(512), 0, stream>>>(enc, encb, ep, h0, c0, Wdec, v,
        Wp0, Wqih, Wqhh, bih, bhh, Wout, bout, out);
  else
    k_main<false><<<dim3(256), dim3(512), 0, stream>>>(enc, encb, ep, h0, c0, Wdec, v,
        Wp0, Wqih, Wqhh, bih, bhh, Wout, bout, out);
}